// Round 12
// baseline (459.598 us; speedup 1.0000x reference)
//
#include <hip/hip_runtime.h>
#include <hip/hip_bf16.h>

#define NN 200000
#define NE 400000
#define NG 8000
#define HID 128
#define OUTD 256
#define NODE_TOT 178
#define NCOMBO 264          // 22*6*2 distinct edge-attr triples
#define SCAN_NB 196         // ceil(NN/1024)

typedef __attribute__((ext_vector_type(8))) short bfrag8;
typedef __attribute__((ext_vector_type(4))) short bfrag4;
typedef __attribute__((ext_vector_type(4))) float f32x4;
typedef unsigned short ushort_t;

__constant__ int c_noff[10] = {0,119,128,139,151,161,166,174,176,178};

__device__ __forceinline__ ushort_t f2bf(float f) {
  union { float f; unsigned u; } x; x.f = f;
  unsigned r = x.u + 0x7fffu + ((x.u >> 16) & 1u);
  return (ushort_t)(r >> 16);
}
__device__ __forceinline__ float bf2f(ushort_t u) {
  union { unsigned u; float f; } x; x.u = ((unsigned)u) << 16;
  return x.f;
}

// Fused setup: blocks [0,178) PN rows; [178,442) PE3b combos (direct from
// inputs); [442,586) weight packing (flat t over 18432).
__global__ __launch_bounds__(128) void setup_tables(
    const float* __restrict__ node_emb, const float* __restrict__ edge_emb,
    const float* __restrict__ npw, const float* __restrict__ npb,
    const float* __restrict__ epw, const float* __restrict__ epb,
    const float* __restrict__ w1, const float* __restrict__ w2,
    float* __restrict__ PN, unsigned* __restrict__ pe3b,
    ushort_t* __restrict__ pw)
{
  int b = blockIdx.x, tid = threadIdx.x;
  if (b < NODE_TOT) {
    int r = b, d = tid;
    int c = 0;
    while (r >= c_noff[c+1]) c++;
    float acc = (c == 0) ? npb[d] : 0.f;
    const float* er = node_emb + r*HID;
    const float* wb = npw + (size_t)(c*HID)*HID + d;
    for (int k = 0; k < HID; k++) acc += er[k] * wb[(size_t)k*HID];
    PN[r*HID + d] = acc;
  } else if (b < NODE_TOT + NCOMBO) {
    if (tid >= 64) return;
    int c = b - NODE_TOT, lane = tid;
    int a2 = c & 1, a1 = (c >> 1) % 6, a0 = (c >> 1) / 6;
    int row[3] = { a0, 22 + a1, 28 + a2 };
    float v0 = epb[lane*2], v1 = epb[lane*2 + 1];
    #pragma unroll
    for (int f = 0; f < 3; f++) {
      const float* er = edge_emb + row[f]*HID;
      const float* wb = epw + (size_t)(f*HID)*HID;
      for (int k = 0; k < HID; k++) {
        float e = er[k];
        v0 += e * wb[(size_t)k*HID + lane*2];
        v1 += e * wb[(size_t)k*HID + lane*2 + 1];
      }
    }
    pe3b[c*64 + lane] = (unsigned)f2bf(v0) | ((unsigned)f2bf(v1) << 16);
  } else {
    // pack: w1 A-frag of W1^T (16x16x32), w2 A-frag of W2^T (16x16x16)
    int t = (b - NODE_TOT - NCOMBO)*128 + tid;   // 18432 total
    if (t < 6144) {
      int lane = t & 63, tile = (t >> 6) & 31, layer = t >> 11;
      int nt = tile >> 2, kt = tile & 3;
      int n  = nt*16 + (lane & 15);
      int k0 = kt*32 + ((lane >> 4) << 3);
      const float* src = w1 + (size_t)layer*HID*HID;
      ushort_t* dst = pw + (size_t)layer*32768 + (size_t)tile*512 + lane*8;
      #pragma unroll
      for (int j = 0; j < 8; j++) dst[j] = f2bf(src[(size_t)(k0+j)*HID + n]);
    } else {
      int t2 = t - 6144;
      int lane = t2 & 63, frag = (t2 >> 6) & 63, layer = t2 >> 12;
      int it = frag >> 3, kk = frag & 7;
      int i  = it*16 + (lane & 15);
      int k0 = kk*16 + ((lane >> 4) << 2);
      const float* src = w2 + (size_t)layer*HID*HID;
      ushort_t* dst = pw + (size_t)layer*32768 + 16384 + (size_t)frag*256 + lane*4;
      #pragma unroll
      for (int j = 0; j < 4; j++) dst[j] = f2bf(src[(size_t)(k0+j)*HID + i]);
    }
  }
}

// 4 dims/thread: f32x4 table loads, 4 ILP chains, 8B packed bf16 store
__global__ __launch_bounds__(256) void node_embed(const int* __restrict__ x,
                                                  const float* __restrict__ PN,
                                                  ushort_t* __restrict__ h)
{
  int gid = blockIdx.x*256 + threadIdx.x;   // NN*32 total, exact
  int i = gid >> 5, d0 = (gid & 31) << 2;
  const int* xr = x + i*9;
  f32x4 acc = {0.f, 0.f, 0.f, 0.f};
  #pragma unroll
  for (int c = 0; c < 9; c++)
    acc += *(const f32x4*)&PN[(c_noff[c] + xr[c])*HID + d0];
  uint2 pk;
  pk.x = (unsigned)f2bf(acc[0]) | ((unsigned)f2bf(acc[1]) << 16);
  pk.y = (unsigned)f2bf(acc[2]) | ((unsigned)f2bf(acc[3]) << 16);
  *(uint2*)&h[(size_t)i*HID + d0] = pk;
}

// ---------- CSR build (once per launch, reused for all 3 layers) ----------
__global__ __launch_bounds__(256) void hist(const int* __restrict__ ei, int* __restrict__ deg) {
  int e = blockIdx.x*256 + threadIdx.x;
  if (e < NE) atomicAdd(&deg[ei[NE + e]], 1);
}

__global__ __launch_bounds__(256) void scan1(const int* __restrict__ deg,
                                             int* __restrict__ rowptr,
                                             int* __restrict__ bsum)
{
  __shared__ int sd[256];
  int b = blockIdx.x, t = threadIdx.x;
  int idx0 = b*1024 + t*4;
  int v[4]; int s = 0;
  #pragma unroll
  for (int j = 0; j < 4; j++) { int i = idx0 + j; v[j] = (i < NN) ? deg[i] : 0; s += v[j]; }
  sd[t] = s; __syncthreads();
  for (int off = 1; off < 256; off <<= 1) {
    int x = (t >= off) ? sd[t - off] : 0; __syncthreads();
    sd[t] += x; __syncthreads();
  }
  int run = (t > 0) ? sd[t-1] : 0;
  #pragma unroll
  for (int j = 0; j < 4; j++) { int i = idx0 + j; run += v[j]; if (i < NN) rowptr[i+1] = run; }
  if (t == 255) bsum[b] = sd[255];
}

__global__ __launch_bounds__(256) void scan2(int* __restrict__ bsum) {
  __shared__ int sd[256];
  int t = threadIdx.x;
  sd[t] = (t < SCAN_NB) ? bsum[t] : 0; __syncthreads();
  for (int off = 1; off < 256; off <<= 1) {
    int x = (t >= off) ? sd[t - off] : 0; __syncthreads();
    sd[t] += x; __syncthreads();
  }
  if (t < SCAN_NB) bsum[t] = sd[t];    // inclusive
}

// adds block offsets AND materializes cursor[i] = rowptr[i]
__global__ __launch_bounds__(256) void scan3(int* __restrict__ rowptr,
                                             const int* __restrict__ bsum,
                                             int* __restrict__ cursor)
{
  int b = blockIdx.x, t = threadIdx.x;
  int add = (b > 0) ? bsum[b-1] : 0;
  if (b == 0 && t == 0) { rowptr[0] = 0; cursor[0] = 0; }
  int idx0 = b*1024 + t*4;
  #pragma unroll
  for (int j = 0; j < 4; j++) {
    int i = idx0 + j;
    if (i < NN) {
      int v = rowptr[i+1] + add;
      rowptr[i+1] = v;
      cursor[i+1] = v;
    }
  }
}

// elist[pos] = src | (combo<<18); dloc[pos] = dst & 63 (int: SMEM-loadable)
__global__ __launch_bounds__(256) void scatter_e(const int* __restrict__ ei,
                                                 const int* __restrict__ ea,
                                                 int* __restrict__ cursor,
                                                 unsigned* __restrict__ elist,
                                                 int* __restrict__ dloc)
{
  int e = blockIdx.x*256 + threadIdx.x;
  if (e >= NE) return;
  int src = ei[e], dst = ei[NE + e];
  const int* ar = ea + e*3;
  unsigned combo = (unsigned)((ar[0]*6 + ar[1])*2 + ar[2]);
  int pos = atomicAdd(&cursor[dst], 1);
  elist[pos] = (unsigned)src | (combo << 18);
  dloc[pos] = dst & 63;
}

// Fused GINE layer. Wave w owns rows [blk*64+w*16, +16) and their contiguous
// edge range. Phase A: flat 16-deep pipeline, scalar (s_load) edge metadata,
// sorted-row serial accumulate with uniform-branch flush -> bf16 LDS slice
// (stride 136, free 2-way). Phase B: z = hin+agg, two register GEMMs.
// LAST: skip hout; rows -> LDS (after barrier) + segmented pool into gf.
// launch_bounds(256,6): 6 blocks/CU (VGPR cap 85; LDS 6x17.4KB=104KB) for
// 1.5x resident waves -> more outstanding gathers.
template<bool LAST>
__global__ __launch_bounds__(256, 6) void gine_layer(
    const ushort_t* __restrict__ hin, ushort_t* __restrict__ hout,
    const int* __restrict__ rowptr, const unsigned* __restrict__ elist,
    const int* __restrict__ dloc,
    const unsigned* __restrict__ pe3b,
    const ushort_t* __restrict__ pw,
    const float* __restrict__ b1, const float* __restrict__ b2,
    const int* __restrict__ batch, float* __restrict__ gf)
{
  __shared__ ushort_t aggs[64*136];
  __shared__ int bids[64];
  int tid = threadIdx.x;
  int w = tid >> 6, lane = tid & 63;
  int q = lane >> 4;
  int rb = blockIdx.x*64 + w*16;            // wave's 16 rows (NN%64==0)
  const unsigned* h2 = (const unsigned*)hin;

  if (LAST && tid < 64) bids[tid] = batch[blockIdx.x*64 + tid];

  // pre-zero own 16 rows (covers empty rows)
  #pragma unroll
  for (int r = 0; r < 16; r++)
    ((unsigned*)&aggs[(w*16 + r)*136])[lane] = 0;

  // ---- Phase A: flat 16-deep edge pipeline, scalar metadata ----
  int s = __builtin_amdgcn_readfirstlane(rowptr[rb]);
  int E = __builtin_amdgcn_readfirstlane(rowptr[rb + 16]);
  int cur = -1;                             // block-local row of open accumulator
  float ax = 0.f, ay = 0.f;

  auto proc = [&](int dl, unsigned hv, unsigned tt) {
    int dlu = __builtin_amdgcn_readfirstlane(dl);
    if (dlu != cur) {                       // uniform branch; one flush per row
      if (cur >= 0)
        ((unsigned*)&aggs[cur*136])[lane] =
            (unsigned)f2bf(ax) | ((unsigned)f2bf(ay) << 16);
      cur = dlu; ax = 0.f; ay = 0.f;
    }
    ax += fmaxf(bf2f((ushort_t)(hv & 0xffff)) + bf2f((ushort_t)(tt & 0xffff)), 0.f);
    ay += fmaxf(bf2f((ushort_t)(hv >> 16)) + bf2f((ushort_t)(tt >> 16)), 0.f);
  };

  int j = s;
  for (; j + 15 < E; j += 16) {
    unsigned pk[16]; int dl[16]; unsigned hv[16], tt[16];
    #pragma unroll
    for (int k = 0; k < 16; k++) { pk[k] = elist[j+k]; dl[k] = dloc[j+k]; }
    #pragma unroll
    for (int k = 0; k < 16; k++) {
      hv[k] = h2[(size_t)(pk[k] & 0x3ffff)*64 + lane];
      tt[k] = pe3b[(pk[k] >> 18)*64 + lane];
    }
    #pragma unroll
    for (int k = 0; k < 16; k++) proc(dl[k], hv[k], tt[k]);
  }
  for (; j < E; ++j) {
    unsigned pk = elist[j];
    int dl = dloc[j];
    unsigned hv = h2[(size_t)(pk & 0x3ffff)*64 + lane];
    unsigned tt = pe3b[(pk >> 18)*64 + lane];
    proc(dl, hv, tt);
  }
  if (cur >= 0)
    ((unsigned*)&aggs[cur*136])[lane] =
        (unsigned)f2bf(ax) | ((unsigned)f2bf(ay) << 16);

  // ---- Phase B: z = hin + agg; two register GEMMs ----
  int n = rb + (lane & 15);                 // this lane's z-row
  int acol = q << 3;

  bfrag8 afr[4];
  #pragma unroll
  for (int kt = 0; kt < 4; kt++) {
    int c = kt*32 + acol;
    bfrag8 hfr = *(const bfrag8*)(hin + (size_t)n*HID + c);
    bfrag8 gfr = *(const bfrag8*)&aggs[(w*16 + (lane & 15))*136 + c];
    bfrag8 fr;
    #pragma unroll
    for (int j2 = 0; j2 < 8; j2++)
      fr[j2] = (short)f2bf(bf2f((ushort_t)hfr[j2]) + bf2f((ushort_t)gfr[j2]));
    afr[kt] = fr;
  }

  if (LAST) __syncthreads();                // all aggs reads done before reuse

  const bfrag8* w1f = (const bfrag8*)pw;              // 32 frags (A of W1^T)
  const bfrag4* w2f = (const bfrag4*)(pw + 16384);    // 64 frags (A of W2^T)

  f32x4 acc1[8];
  #pragma unroll
  for (int nt = 0; nt < 8; nt++)
    acc1[nt] = *(const f32x4*)&b1[nt*16 + q*4];
  #pragma unroll
  for (int kt = 0; kt < 4; kt++)
    #pragma unroll
    for (int nt = 0; nt < 8; nt++)
      acc1[nt] = __builtin_amdgcn_mfma_f32_16x16x32_bf16(w1f[(nt*4+kt)*64 + lane], afr[kt], acc1[nt], 0, 0, 0);

  bfrag4 t4[8];
  #pragma unroll
  for (int kk = 0; kk < 8; kk++) {
    bfrag4 v;
    #pragma unroll
    for (int r = 0; r < 4; r++) v[r] = (short)f2bf(fmaxf(acc1[kk][r], 0.f));
    t4[kk] = v;
  }

  #pragma unroll
  for (int it = 0; it < 8; it++) {
    f32x4 acc2 = *(const f32x4*)&b2[it*16 + q*4];
    #pragma unroll
    for (int kk = 0; kk < 8; kk++)
      acc2 = __builtin_amdgcn_mfma_f32_16x16x16bf16_1k(w2f[(it*8+kk)*64 + lane], t4[kk], acc2, 0, 0, 0);
    uint2 pk;
    pk.x = (unsigned)f2bf(fmaxf(acc2[0], 0.f)) | ((unsigned)f2bf(fmaxf(acc2[1], 0.f)) << 16);
    pk.y = (unsigned)f2bf(fmaxf(acc2[2], 0.f)) | ((unsigned)f2bf(fmaxf(acc2[3], 0.f)) << 16);
    if (LAST) {
      *(uint2*)&aggs[(w*16 + (lane & 15))*136 + it*16 + q*4] = pk;
    } else {
      *(uint2*)&hout[(size_t)n*HID + it*16 + q*4] = pk;
    }
  }

  if (LAST) {
    __syncthreads();
    // segmented pool over 64 sorted-batch rows; uniform branch per wave
    int d = tid & 127, rh = tid >> 7;
    float acc = 0.f;
    int curg = bids[rh*32];
    for (int r = 0; r < 32; r++) {
      int row = rh*32 + r;
      int g = bids[row];
      if (g != curg) {
        atomicAdd(&gf[(size_t)curg*HID + d], acc);
        acc = 0.f; curg = g;
      }
      acc += bf2f(aggs[row*136 + d]);
    }
    atomicAdd(&gf[(size_t)curg*HID + d], acc);
  }
}

__global__ __launch_bounds__(256) void final_proj(const float* __restrict__ gf,
                                                  const float* __restrict__ W,
                                                  const float* __restrict__ b,
                                                  float* __restrict__ out)
{
  __shared__ float gls[16*128];
  __shared__ float part[16][4];
  int tid = threadIdx.x;
  int gbase = blockIdx.x*16;
  for (int idx = tid; idx < 2048; idx += 256) gls[idx] = gf[(size_t)gbase*128 + idx];
  __syncthreads();
  float acc[16];
  #pragma unroll
  for (int g = 0; g < 16; g++) acc[g] = 0.f;
  for (int k = 0; k < 128; k++) {
    float wv = W[(size_t)k*256 + tid];
    #pragma unroll
    for (int g = 0; g < 16; g++) acc[g] += gls[g*128 + k] * wv;
  }
  float bj = b[tid];
  int wid = tid >> 6, lane = tid & 63;
  #pragma unroll
  for (int g = 0; g < 16; g++) {
    acc[g] += bj;
    float s = acc[g]*acc[g];
    #pragma unroll
    for (int off = 32; off > 0; off >>= 1) s += __shfl_xor(s, off, 64);
    if (lane == 0) part[g][wid] = s;
  }
  __syncthreads();
  #pragma unroll
  for (int g = 0; g < 16; g++) {
    float S = part[g][0] + part[g][1] + part[g][2] + part[g][3];
    float rn = 1.f / fmaxf(sqrtf(S), 1e-12f);
    out[(size_t)(gbase + g)*256 + tid] = acc[g]*rn;
  }
}

__global__ __launch_bounds__(256) void ws_diag(float* __restrict__ out, int n, float wsval) {
  int i = blockIdx.x*256 + threadIdx.x;
  if (i < n) out[i] = (i == 0) ? wsval : 0.f;
}

extern "C" void kernel_launch(void* const* d_in, const int* in_sizes, int n_in,
                              void* d_out, int out_size, void* d_ws, size_t ws_size,
                              hipStream_t stream)
{
  const int*   x     = (const int*)d_in[0];
  const int*   ea    = (const int*)d_in[1];
  const int*   ei    = (const int*)d_in[2];
  const int*   batch = (const int*)d_in[3];
  const float* nemb  = (const float*)d_in[4];
  const float* eemb  = (const float*)d_in[5];
  const float* npw   = (const float*)d_in[6];
  const float* npb   = (const float*)d_in[7];
  const float* epw   = (const float*)d_in[8];
  const float* epb   = (const float*)d_in[9];
  const float* w1    = (const float*)d_in[10];
  const float* b1    = (const float*)d_in[11];
  const float* w2    = (const float*)d_in[12];
  const float* b2    = (const float*)d_in[13];
  const float* pjw   = (const float*)d_in[14];
  const float* pjb   = (const float*)d_in[15];
  float* out = (float*)d_out;

  char* ws = (char*)d_ws;
  size_t off = 0;
  auto carve = [&](size_t bytes) -> char* {
    char* p = ws + off;
    off = (off + bytes + 255) & ~(size_t)255;
    return p;
  };
  float*    PN     = (float*)carve((size_t)NODE_TOT*HID*4);
  unsigned* PE3b   = (unsigned*)carve((size_t)NCOMBO*64*4);   // bf16 pairs, 67.6 KB
  ushort_t* PW     = (ushort_t*)carve((size_t)3*32768*2);
  ushort_t* hA     = (ushort_t*)carve((size_t)NN*HID*2);      // 51.2 MB
  ushort_t* hB     = (ushort_t*)carve((size_t)NN*HID*2);      // 51.2 MB
  int*      deg    = (int*)carve((size_t)NN*4);               // adjacent to gf
  float*    gf     = (float*)carve((size_t)NG*HID*4);         // one memset for both
  int*      rowptr = (int*)carve((size_t)(NN+1)*4);
  int*      cursor = (int*)carve((size_t)(NN+1)*4);
  int*      bsum   = (int*)carve((size_t)SCAN_NB*4);
  unsigned* elist  = (unsigned*)carve((size_t)NE*4);
  int*      dlc    = (int*)carve((size_t)NE*4);

  if (off > ws_size) {
    ws_diag<<<(out_size + 255)/256, 256, 0, stream>>>(out, out_size, (float)ws_size);
    return;
  }

  setup_tables<<<NODE_TOT + NCOMBO + 144, 128, 0, stream>>>(
      nemb, eemb, npw, npb, epw, epb, w1, w2, PN, PE3b, PW);
  node_embed<<<(NN*32)/256, 256, 0, stream>>>(x, PN, hA);

  // CSR build (once); deg+gf zeroed in one contiguous memset
  hipMemsetAsync(deg, 0, (size_t)NN*4 + (size_t)NG*HID*4, stream);
  hist<<<(NE + 255)/256, 256, 0, stream>>>(ei, deg);
  scan1<<<SCAN_NB, 256, 0, stream>>>(deg, rowptr, bsum);
  scan2<<<1, 256, 0, stream>>>(bsum);
  scan3<<<SCAN_NB, 256, 0, stream>>>(rowptr, bsum, cursor);
  scatter_e<<<(NE + 255)/256, 256, 0, stream>>>(ei, ea, cursor, elist, dlc);

  gine_layer<false><<<NN/64, 256, 0, stream>>>(hA, hB, rowptr, elist, dlc, PE3b,
                                               PW, b1, b2, batch, gf);
  gine_layer<false><<<NN/64, 256, 0, stream>>>(hB, hA, rowptr, elist, dlc, PE3b,
                                               PW + 32768, b1 + HID, b2 + HID, batch, gf);
  gine_layer<true><<<NN/64, 256, 0, stream>>>(hA, hB, rowptr, elist, dlc, PE3b,
                                              PW + 65536, b1 + 2*HID, b2 + 2*HID, batch, gf);

  final_proj<<<NG/16, 256, 0, stream>>>(gf, pjw, pjb, out);
}

// Round 13
// 430.966 us; speedup vs baseline: 1.0664x; 1.0664x over previous
//
#include <hip/hip_runtime.h>
#include <hip/hip_bf16.h>

#define NN 200000
#define NE 400000
#define NG 8000
#define HID 128
#define OUTD 256
#define NODE_TOT 178
#define NCOMBO 264          // 22*6*2 distinct edge-attr triples
#define SCAN_NB 196         // ceil(NN/1024)

typedef __attribute__((ext_vector_type(8))) short bfrag8;
typedef __attribute__((ext_vector_type(4))) short bfrag4;
typedef __attribute__((ext_vector_type(4))) float f32x4;
typedef unsigned short ushort_t;
typedef unsigned long long u64;

__constant__ int c_noff[10] = {0,119,128,139,151,161,166,174,176,178};

__device__ __forceinline__ ushort_t f2bf(float f) {
  union { float f; unsigned u; } x; x.f = f;
  unsigned r = x.u + 0x7fffu + ((x.u >> 16) & 1u);
  return (ushort_t)(r >> 16);
}
__device__ __forceinline__ float bf2f(ushort_t u) {
  union { unsigned u; float f; } x; x.u = ((unsigned)u) << 16;
  return x.f;
}

// Fused setup+hist: blocks [0,178) PN rows; [178,442) PE3b combos;
// [442,586) weight packing; [586,3711) degree histogram (128 edges/block).
__global__ __launch_bounds__(128) void setup_hist(
    const float* __restrict__ node_emb, const float* __restrict__ edge_emb,
    const float* __restrict__ npw, const float* __restrict__ npb,
    const float* __restrict__ epw, const float* __restrict__ epb,
    const float* __restrict__ w1, const float* __restrict__ w2,
    const int* __restrict__ ei,
    float* __restrict__ PN, unsigned* __restrict__ pe3b,
    ushort_t* __restrict__ pw, int* __restrict__ deg)
{
  int b = blockIdx.x, tid = threadIdx.x;
  if (b < NODE_TOT) {
    int r = b, d = tid;
    int c = 0;
    while (r >= c_noff[c+1]) c++;
    float acc = (c == 0) ? npb[d] : 0.f;
    const float* er = node_emb + r*HID;
    const float* wb = npw + (size_t)(c*HID)*HID + d;
    for (int k = 0; k < HID; k++) acc += er[k] * wb[(size_t)k*HID];
    PN[r*HID + d] = acc;
  } else if (b < NODE_TOT + NCOMBO) {
    if (tid >= 64) return;
    int c = b - NODE_TOT, lane = tid;
    int a2 = c & 1, a1 = (c >> 1) % 6, a0 = (c >> 1) / 6;
    int row[3] = { a0, 22 + a1, 28 + a2 };
    float v0 = epb[lane*2], v1 = epb[lane*2 + 1];
    #pragma unroll
    for (int f = 0; f < 3; f++) {
      const float* er = edge_emb + row[f]*HID;
      const float* wb = epw + (size_t)(f*HID)*HID;
      for (int k = 0; k < HID; k++) {
        float e = er[k];
        v0 += e * wb[(size_t)k*HID + lane*2];
        v1 += e * wb[(size_t)k*HID + lane*2 + 1];
      }
    }
    pe3b[c*64 + lane] = (unsigned)f2bf(v0) | ((unsigned)f2bf(v1) << 16);
  } else if (b < NODE_TOT + NCOMBO + 144) {
    // pack: w1 A-frag of W1^T (16x16x32), w2 A-frag of W2^T (16x16x16)
    int t = (b - NODE_TOT - NCOMBO)*128 + tid;   // 18432 total
    if (t < 6144) {
      int lane = t & 63, tile = (t >> 6) & 31, layer = t >> 11;
      int nt = tile >> 2, kt = tile & 3;
      int n  = nt*16 + (lane & 15);
      int k0 = kt*32 + ((lane >> 4) << 3);
      const float* src = w1 + (size_t)layer*HID*HID;
      ushort_t* dst = pw + (size_t)layer*32768 + (size_t)tile*512 + lane*8;
      #pragma unroll
      for (int j = 0; j < 8; j++) dst[j] = f2bf(src[(size_t)(k0+j)*HID + n]);
    } else {
      int t2 = t - 6144;
      int lane = t2 & 63, frag = (t2 >> 6) & 63, layer = t2 >> 12;
      int it = frag >> 3, kk = frag & 7;
      int i  = it*16 + (lane & 15);
      int k0 = kk*16 + ((lane >> 4) << 2);
      const float* src = w2 + (size_t)layer*HID*HID;
      ushort_t* dst = pw + (size_t)layer*32768 + 16384 + (size_t)frag*256 + lane*4;
      #pragma unroll
      for (int j = 0; j < 4; j++) dst[j] = f2bf(src[(size_t)(k0+j)*HID + i]);
    }
  } else {
    int e = (b - NODE_TOT - NCOMBO - 144)*128 + tid;   // NE = 3125*128 exact
    atomicAdd(&deg[ei[NE + e]], 1);
  }
}

// ---------- scans ----------
__global__ __launch_bounds__(256) void scan1(const int* __restrict__ deg,
                                             int* __restrict__ rowptr,
                                             int* __restrict__ bsum)
{
  __shared__ int sd[256];
  int b = blockIdx.x, t = threadIdx.x;
  int idx0 = b*1024 + t*4;
  int v[4]; int s = 0;
  #pragma unroll
  for (int j = 0; j < 4; j++) { int i = idx0 + j; v[j] = (i < NN) ? deg[i] : 0; s += v[j]; }
  sd[t] = s; __syncthreads();
  for (int off = 1; off < 256; off <<= 1) {
    int x = (t >= off) ? sd[t - off] : 0; __syncthreads();
    sd[t] += x; __syncthreads();
  }
  int run = (t > 0) ? sd[t-1] : 0;
  #pragma unroll
  for (int j = 0; j < 4; j++) { int i = idx0 + j; run += v[j]; if (i < NN) rowptr[i+1] = run; }
  if (t == 255) bsum[b] = sd[255];
}

__global__ __launch_bounds__(256) void scan2(int* __restrict__ bsum) {
  __shared__ int sd[256];
  int t = threadIdx.x;
  sd[t] = (t < SCAN_NB) ? bsum[t] : 0; __syncthreads();
  for (int off = 1; off < 256; off <<= 1) {
    int x = (t >= off) ? sd[t - off] : 0; __syncthreads();
    sd[t] += x; __syncthreads();
  }
  if (t < SCAN_NB) bsum[t] = sd[t];    // inclusive
}

__global__ __launch_bounds__(256) void scan3(int* __restrict__ rowptr,
                                             const int* __restrict__ bsum,
                                             int* __restrict__ cursor)
{
  int b = blockIdx.x, t = threadIdx.x;
  int add = (b > 0) ? bsum[b-1] : 0;
  if (b == 0 && t == 0) { rowptr[0] = 0; cursor[0] = 0; }
  int idx0 = b*1024 + t*4;
  #pragma unroll
  for (int j = 0; j < 4; j++) {
    int i = idx0 + j;
    if (i < NN) {
      int v = rowptr[i+1] + add;
      rowptr[i+1] = v;
      cursor[i+1] = v;
    }
  }
}

// Fused scatter + node_embed.
// Blocks [0,1563): epack[pos] = src | combo<<18 | (u64)(dst&63)<<32 (one 8B store).
// Blocks [1563,14063): node_embed, 8 dims/thread (2x f32x4 loads, 16B store).
__global__ __launch_bounds__(256) void scatter_embed(
    const int* __restrict__ ei, const int* __restrict__ ea,
    int* __restrict__ cursor, u64* __restrict__ epack,
    const int* __restrict__ x, const float* __restrict__ PN,
    ushort_t* __restrict__ h)
{
  int b = blockIdx.x, tid = threadIdx.x;
  if (b < 1563) {
    int e = b*256 + tid;
    if (e >= NE) return;
    int src = ei[e], dst = ei[NE + e];
    const int* ar = ea + e*3;
    unsigned combo = (unsigned)((ar[0]*6 + ar[1])*2 + ar[2]);
    int pos = atomicAdd(&cursor[dst], 1);
    epack[pos] = (u64)((unsigned)src | (combo << 18)) | ((u64)(dst & 63) << 32);
  } else {
    int gid = (b - 1563)*256 + tid;        // NN*16 total, exact (12500 blocks)
    int i = gid >> 4, d0 = (gid & 15) << 3;
    const int* xr = x + i*9;
    f32x4 a0 = {0.f,0.f,0.f,0.f}, a1 = {0.f,0.f,0.f,0.f};
    #pragma unroll
    for (int c = 0; c < 9; c++) {
      const f32x4* p = (const f32x4*)&PN[(c_noff[c] + xr[c])*HID + d0];
      a0 += p[0]; a1 += p[1];
    }
    uint4 pk;
    pk.x = (unsigned)f2bf(a0[0]) | ((unsigned)f2bf(a0[1]) << 16);
    pk.y = (unsigned)f2bf(a0[2]) | ((unsigned)f2bf(a0[3]) << 16);
    pk.z = (unsigned)f2bf(a1[0]) | ((unsigned)f2bf(a1[1]) << 16);
    pk.w = (unsigned)f2bf(a1[2]) | ((unsigned)f2bf(a1[3]) << 16);
    *(uint4*)&h[(size_t)i*HID + d0] = pk;
  }
}

// Fused GINE layer (R11 config: 4 blocks/CU, 12-deep, scalar metadata).
// Wave w owns rows [blk*64+w*16, +16) and their contiguous edge range.
// Phase A: flat 12-deep pipeline over epack (u64 = src|combo<<18 | dloc<<32),
// sorted-row serial accumulate, uniform-branch flush -> bf16 LDS (stride 136).
// Phase B: z = hin+agg, two register GEMMs. LAST: fused segmented pool.
template<bool LAST>
__global__ __launch_bounds__(256, 4) void gine_layer(
    const ushort_t* __restrict__ hin, ushort_t* __restrict__ hout,
    const int* __restrict__ rowptr, const u64* __restrict__ epack,
    const unsigned* __restrict__ pe3b,
    const ushort_t* __restrict__ pw,
    const float* __restrict__ b1, const float* __restrict__ b2,
    const int* __restrict__ batch, float* __restrict__ gf)
{
  __shared__ ushort_t aggs[64*136];
  __shared__ int bids[64];
  int tid = threadIdx.x;
  int w = tid >> 6, lane = tid & 63;
  int q = lane >> 4;
  int rb = blockIdx.x*64 + w*16;            // wave's 16 rows (NN%64==0)
  const unsigned* h2 = (const unsigned*)hin;

  if (LAST && tid < 64) bids[tid] = batch[blockIdx.x*64 + tid];

  // pre-zero own 16 rows (covers empty rows)
  #pragma unroll
  for (int r = 0; r < 16; r++)
    ((unsigned*)&aggs[(w*16 + r)*136])[lane] = 0;

  // ---- Phase A: flat 12-deep edge pipeline, scalar metadata ----
  int s = __builtin_amdgcn_readfirstlane(rowptr[rb]);
  int E = __builtin_amdgcn_readfirstlane(rowptr[rb + 16]);
  int cur = -1;                             // block-local row of open accumulator
  float ax = 0.f, ay = 0.f;

  auto proc = [&](int dl, unsigned hv, unsigned tt) {
    int dlu = __builtin_amdgcn_readfirstlane(dl);
    if (dlu != cur) {                       // uniform branch; one flush per row
      if (cur >= 0)
        ((unsigned*)&aggs[cur*136])[lane] =
            (unsigned)f2bf(ax) | ((unsigned)f2bf(ay) << 16);
      cur = dlu; ax = 0.f; ay = 0.f;
    }
    ax += fmaxf(bf2f((ushort_t)(hv & 0xffff)) + bf2f((ushort_t)(tt & 0xffff)), 0.f);
    ay += fmaxf(bf2f((ushort_t)(hv >> 16)) + bf2f((ushort_t)(tt >> 16)), 0.f);
  };

  int j = s;
  for (; j + 11 < E; j += 12) {
    u64 ep[12]; unsigned hv[12], tt[12];
    #pragma unroll
    for (int k = 0; k < 12; k++) ep[k] = epack[j+k];
    #pragma unroll
    for (int k = 0; k < 12; k++) {
      unsigned pk = (unsigned)ep[k];
      hv[k] = h2[(size_t)(pk & 0x3ffff)*64 + lane];
      tt[k] = pe3b[(pk >> 18)*64 + lane];
    }
    #pragma unroll
    for (int k = 0; k < 12; k++) proc((int)(ep[k] >> 32), hv[k], tt[k]);
  }
  for (; j < E; ++j) {
    u64 ep = epack[j];
    unsigned pk = (unsigned)ep;
    unsigned hv = h2[(size_t)(pk & 0x3ffff)*64 + lane];
    unsigned tt = pe3b[(pk >> 18)*64 + lane];
    proc((int)(ep >> 32), hv, tt);
  }
  if (cur >= 0)
    ((unsigned*)&aggs[cur*136])[lane] =
        (unsigned)f2bf(ax) | ((unsigned)f2bf(ay) << 16);

  // ---- Phase B: z = hin + agg; two register GEMMs ----
  int n = rb + (lane & 15);                 // this lane's z-row
  int acol = q << 3;

  bfrag8 afr[4];
  #pragma unroll
  for (int kt = 0; kt < 4; kt++) {
    int c = kt*32 + acol;
    bfrag8 hfr = *(const bfrag8*)(hin + (size_t)n*HID + c);
    bfrag8 gfr = *(const bfrag8*)&aggs[(w*16 + (lane & 15))*136 + c];
    bfrag8 fr;
    #pragma unroll
    for (int j2 = 0; j2 < 8; j2++)
      fr[j2] = (short)f2bf(bf2f((ushort_t)hfr[j2]) + bf2f((ushort_t)gfr[j2]));
    afr[kt] = fr;
  }

  if (LAST) __syncthreads();                // all aggs reads done before reuse

  const bfrag8* w1f = (const bfrag8*)pw;              // 32 frags (A of W1^T)
  const bfrag4* w2f = (const bfrag4*)(pw + 16384);    // 64 frags (A of W2^T)

  f32x4 acc1[8];
  #pragma unroll
  for (int nt = 0; nt < 8; nt++)
    acc1[nt] = *(const f32x4*)&b1[nt*16 + q*4];
  #pragma unroll
  for (int kt = 0; kt < 4; kt++)
    #pragma unroll
    for (int nt = 0; nt < 8; nt++)
      acc1[nt] = __builtin_amdgcn_mfma_f32_16x16x32_bf16(w1f[(nt*4+kt)*64 + lane], afr[kt], acc1[nt], 0, 0, 0);

  bfrag4 t4[8];
  #pragma unroll
  for (int kk = 0; kk < 8; kk++) {
    bfrag4 v;
    #pragma unroll
    for (int r = 0; r < 4; r++) v[r] = (short)f2bf(fmaxf(acc1[kk][r], 0.f));
    t4[kk] = v;
  }

  #pragma unroll
  for (int it = 0; it < 8; it++) {
    f32x4 acc2 = *(const f32x4*)&b2[it*16 + q*4];
    #pragma unroll
    for (int kk = 0; kk < 8; kk++)
      acc2 = __builtin_amdgcn_mfma_f32_16x16x16bf16_1k(w2f[(it*8+kk)*64 + lane], t4[kk], acc2, 0, 0, 0);
    uint2 pk;
    pk.x = (unsigned)f2bf(fmaxf(acc2[0], 0.f)) | ((unsigned)f2bf(fmaxf(acc2[1], 0.f)) << 16);
    pk.y = (unsigned)f2bf(fmaxf(acc2[2], 0.f)) | ((unsigned)f2bf(fmaxf(acc2[3], 0.f)) << 16);
    if (LAST) {
      *(uint2*)&aggs[(w*16 + (lane & 15))*136 + it*16 + q*4] = pk;
    } else {
      *(uint2*)&hout[(size_t)n*HID + it*16 + q*4] = pk;
    }
  }

  if (LAST) {
    __syncthreads();
    // segmented pool over 64 sorted-batch rows; uniform branch per wave
    int d = tid & 127, rh = tid >> 7;
    float acc = 0.f;
    int curg = bids[rh*32];
    for (int r = 0; r < 32; r++) {
      int row = rh*32 + r;
      int g = bids[row];
      if (g != curg) {
        atomicAdd(&gf[(size_t)curg*HID + d], acc);
        acc = 0.f; curg = g;
      }
      acc += bf2f(aggs[row*136 + d]);
    }
    atomicAdd(&gf[(size_t)curg*HID + d], acc);
  }
}

__global__ __launch_bounds__(256) void final_proj(const float* __restrict__ gf,
                                                  const float* __restrict__ W,
                                                  const float* __restrict__ b,
                                                  float* __restrict__ out)
{
  __shared__ float gls[16*128];
  __shared__ float part[16][4];
  int tid = threadIdx.x;
  int gbase = blockIdx.x*16;
  for (int idx = tid; idx < 2048; idx += 256) gls[idx] = gf[(size_t)gbase*128 + idx];
  __syncthreads();
  float acc[16];
  #pragma unroll
  for (int g = 0; g < 16; g++) acc[g] = 0.f;
  for (int k = 0; k < 128; k++) {
    float wv = W[(size_t)k*256 + tid];
    #pragma unroll
    for (int g = 0; g < 16; g++) acc[g] += gls[g*128 + k] * wv;
  }
  float bj = b[tid];
  int wid = tid >> 6, lane = tid & 63;
  #pragma unroll
  for (int g = 0; g < 16; g++) {
    acc[g] += bj;
    float s = acc[g]*acc[g];
    #pragma unroll
    for (int off = 32; off > 0; off >>= 1) s += __shfl_xor(s, off, 64);
    if (lane == 0) part[g][wid] = s;
  }
  __syncthreads();
  #pragma unroll
  for (int g = 0; g < 16; g++) {
    float S = part[g][0] + part[g][1] + part[g][2] + part[g][3];
    float rn = 1.f / fmaxf(sqrtf(S), 1e-12f);
    out[(size_t)(gbase + g)*256 + tid] = acc[g]*rn;
  }
}

__global__ __launch_bounds__(256) void ws_diag(float* __restrict__ out, int n, float wsval) {
  int i = blockIdx.x*256 + threadIdx.x;
  if (i < n) out[i] = (i == 0) ? wsval : 0.f;
}

extern "C" void kernel_launch(void* const* d_in, const int* in_sizes, int n_in,
                              void* d_out, int out_size, void* d_ws, size_t ws_size,
                              hipStream_t stream)
{
  const int*   x     = (const int*)d_in[0];
  const int*   ea    = (const int*)d_in[1];
  const int*   ei    = (const int*)d_in[2];
  const int*   batch = (const int*)d_in[3];
  const float* nemb  = (const float*)d_in[4];
  const float* eemb  = (const float*)d_in[5];
  const float* npw   = (const float*)d_in[6];
  const float* npb   = (const float*)d_in[7];
  const float* epw   = (const float*)d_in[8];
  const float* epb   = (const float*)d_in[9];
  const float* w1    = (const float*)d_in[10];
  const float* b1    = (const float*)d_in[11];
  const float* w2    = (const float*)d_in[12];
  const float* b2    = (const float*)d_in[13];
  const float* pjw   = (const float*)d_in[14];
  const float* pjb   = (const float*)d_in[15];
  float* out = (float*)d_out;

  char* ws = (char*)d_ws;
  size_t off = 0;
  auto carve = [&](size_t bytes) -> char* {
    char* p = ws + off;
    off = (off + bytes + 255) & ~(size_t)255;
    return p;
  };
  float*    PN     = (float*)carve((size_t)NODE_TOT*HID*4);
  unsigned* PE3b   = (unsigned*)carve((size_t)NCOMBO*64*4);   // bf16 pairs, 67.6 KB
  ushort_t* PW     = (ushort_t*)carve((size_t)3*32768*2);
  ushort_t* hA     = (ushort_t*)carve((size_t)NN*HID*2);      // 51.2 MB
  ushort_t* hB     = (ushort_t*)carve((size_t)NN*HID*2);      // 51.2 MB
  int*      deg    = (int*)carve((size_t)NN*4);               // adjacent to gf
  float*    gf     = (float*)carve((size_t)NG*HID*4);         // one memset for both
  int*      rowptr = (int*)carve((size_t)(NN+1)*4);
  int*      cursor = (int*)carve((size_t)(NN+1)*4);
  int*      bsum   = (int*)carve((size_t)SCAN_NB*4);
  u64*      epack  = (u64*)carve((size_t)NE*8);

  if (off > ws_size) {
    ws_diag<<<(out_size + 255)/256, 256, 0, stream>>>(out, out_size, (float)ws_size);
    return;
  }

  hipMemsetAsync(deg, 0, (size_t)NN*4 + (size_t)NG*HID*4, stream);
  setup_hist<<<NODE_TOT + NCOMBO + 144 + 3125, 128, 0, stream>>>(
      nemb, eemb, npw, npb, epw, epb, w1, w2, ei, PN, PE3b, PW, deg);
  scan1<<<SCAN_NB, 256, 0, stream>>>(deg, rowptr, bsum);
  scan2<<<1, 256, 0, stream>>>(bsum);
  scan3<<<SCAN_NB, 256, 0, stream>>>(rowptr, bsum, cursor);
  scatter_embed<<<1563 + 12500, 256, 0, stream>>>(ei, ea, cursor, epack, x, PN, hA);

  gine_layer<false><<<NN/64, 256, 0, stream>>>(hA, hB, rowptr, epack, PE3b,
                                               PW, b1, b2, batch, gf);
  gine_layer<false><<<NN/64, 256, 0, stream>>>(hB, hA, rowptr, epack, PE3b,
                                               PW + 32768, b1 + HID, b2 + HID, batch, gf);
  gine_layer<true><<<NN/64, 256, 0, stream>>>(hA, hB, rowptr, epack, PE3b,
                                              PW + 65536, b1 + 2*HID, b2 + 2*HID, batch, gf);

  final_proj<<<NG/16, 256, 0, stream>>>(gf, pjw, pjb, out);
}